// Round 1
// baseline (2762.328 us; speedup 1.0000x reference)
//
#include <hip/hip_runtime.h>

// LSTM_18210661335311: 2-layer LSTM (IN=2, H=8) over [B=32768, T=256, 2] fp32,
// + MLP head [2,8]. One thread per batch element. Weights read via uniform
// (scalar) loads from global; state h/c in registers; fully unrolled inner loops.

#define TT   256
#define NB   32768
#define HDIM 8
#define GDIM 32   // 4*H

__device__ __forceinline__ float fexp(float x) {
    return __builtin_amdgcn_exp2f(x * 1.4426950408889634f);
}
__device__ __forceinline__ float frcp(float x) {
    return __builtin_amdgcn_rcpf(x);
}
__device__ __forceinline__ float sigm(float x) {
    return frcp(1.0f + fexp(-x));
}
__device__ __forceinline__ float tanh_(float x) {
    // clamp so fexp never overflows (c-state can grow over 256 steps)
    x = fminf(fmaxf(x, -20.0f), 20.0f);
    float e = fexp(2.0f * x);
    return (e - 1.0f) * frcp(e + 1.0f);
}

__global__ __launch_bounds__(256) void lstm2_kernel(
    const float* __restrict__ input,   // [NB, TT, 2]
    const float* __restrict__ w_ih0,   // [32, 2]
    const float* __restrict__ w_hh0,   // [32, 8]
    const float* __restrict__ b_ih0,   // [32]
    const float* __restrict__ b_hh0,   // [32]
    const float* __restrict__ w_ih1,   // [32, 8]
    const float* __restrict__ w_hh1,   // [32, 8]
    const float* __restrict__ b_ih1,   // [32]
    const float* __restrict__ b_hh1,   // [32]
    const float* __restrict__ w_mlp,   // [2, 8]
    const float* __restrict__ b_mlp,   // [2]
    float* __restrict__ out)           // [NB, 2]
{
    const int b = blockIdx.x * blockDim.x + threadIdx.x;
    const float4* __restrict__ xrow =
        reinterpret_cast<const float4*>(input + (size_t)b * TT * 2);

    float h0[HDIM], c0[HDIM], h1[HDIM], c1[HDIM];
#pragma unroll
    for (int k = 0; k < HDIM; ++k) { h0[k] = 0.f; c0[k] = 0.f; h1[k] = 0.f; c1[k] = 0.f; }

    auto cell = [&](float x0, float x1) {
        // ---- layer 0 ----
        float g0[GDIM];
#pragma unroll
        for (int g = 0; g < GDIM; ++g) {
            float acc = b_ih0[g] + b_hh0[g];
            acc += x0 * w_ih0[g * 2 + 0];
            acc += x1 * w_ih0[g * 2 + 1];
#pragma unroll
            for (int k = 0; k < HDIM; ++k) acc += h0[k] * w_hh0[g * HDIM + k];
            g0[g] = acc;
        }
#pragma unroll
        for (int k = 0; k < HDIM; ++k) {
            float ig = sigm(g0[k]);
            float fg = sigm(g0[HDIM + k]);
            float gg = tanh_(g0[2 * HDIM + k]);
            float og = sigm(g0[3 * HDIM + k]);
            c0[k] = fg * c0[k] + ig * gg;
            h0[k] = og * tanh_(c0[k]);
        }
        // ---- layer 1 ----
        float g1[GDIM];
#pragma unroll
        for (int g = 0; g < GDIM; ++g) {
            float acc = b_ih1[g] + b_hh1[g];
#pragma unroll
            for (int k = 0; k < HDIM; ++k) {
                acc += h0[k] * w_ih1[g * HDIM + k];
                acc += h1[k] * w_hh1[g * HDIM + k];
            }
            g1[g] = acc;
        }
#pragma unroll
        for (int k = 0; k < HDIM; ++k) {
            float ig = sigm(g1[k]);
            float fg = sigm(g1[HDIM + k]);
            float gg = tanh_(g1[2 * HDIM + k]);
            float og = sigm(g1[3 * HDIM + k]);
            c1[k] = fg * c1[k] + ig * gg;
            h1[k] = og * tanh_(c1[k]);
        }
    };

    for (int t = 0; t < TT; t += 2) {
        float4 xv = xrow[t >> 1];
        cell(xv.x, xv.y);
        cell(xv.z, xv.w);
    }

    // ---- MLP head ----
#pragma unroll
    for (int o = 0; o < 2; ++o) {
        float acc = b_mlp[o];
#pragma unroll
        for (int k = 0; k < HDIM; ++k) acc += h1[k] * w_mlp[o * HDIM + k];
        out[b * 2 + o] = acc;
    }
}

extern "C" void kernel_launch(void* const* d_in, const int* in_sizes, int n_in,
                              void* d_out, int out_size, void* d_ws, size_t ws_size,
                              hipStream_t stream) {
    const float* input = (const float*)d_in[0];
    const float* w_ih0 = (const float*)d_in[1];
    const float* w_hh0 = (const float*)d_in[2];
    const float* b_ih0 = (const float*)d_in[3];
    const float* b_hh0 = (const float*)d_in[4];
    const float* w_ih1 = (const float*)d_in[5];
    const float* w_hh1 = (const float*)d_in[6];
    const float* b_ih1 = (const float*)d_in[7];
    const float* b_hh1 = (const float*)d_in[8];
    const float* w_mlp = (const float*)d_in[9];
    const float* b_mlp = (const float*)d_in[10];
    float* out = (float*)d_out;

    dim3 block(256);
    dim3 grid(NB / 256);
    lstm2_kernel<<<grid, block, 0, stream>>>(input, w_ih0, w_hh0, b_ih0, b_hh0,
                                             w_ih1, w_hh1, b_ih1, b_hh1,
                                             w_mlp, b_mlp, out);
}

// Round 2
// 458.863 us; speedup vs baseline: 6.0199x; 6.0199x over previous
//
#include <hip/hip_runtime.h>

// LSTM_18210661335311 — R1: 16 lanes per batch element, register-resident
// pre-permuted weights, all cross-lane via XOR-safe DPP (no LDS, no per-step
// weight loads). Lane layout within each 16-lane DPP row:
//   k   = lane & 7      (hidden index; duplicated across the two 8-halves)
//   rep = (lane>>3)&1   rep0 owns gate rows {k, 8+k} = (i,f); rep1 owns
//                       {16+k, 24+k} = (g,o)  [PyTorch gate order i,f,g,o]
// h-broadcast for the recurrent dot uses regs hp[j] = {h[k^2j], h[k^2j+1]}
// built with quad_perm(^1,^2,^3) + row_ror:4(≡^4) + row_ror:8(≡^8) — all
// patterns are XOR-involutions under the duplicated layout, so DPP rotate
// direction cannot affect correctness; weights are pre-permuted with the
// same XOR index so products pair up exactly.

#define TT 256
#define NB 32768

typedef float v2f __attribute__((ext_vector_type(2)));

#define DPP_XOR1 0xB1   // quad_perm [1,0,3,2]
#define DPP_XOR2 0x4E   // quad_perm [2,3,0,1]
#define DPP_XOR3 0x1B   // quad_perm [3,2,1,0]
#define DPP_ROR4 0x124  // row_ror:4  == k^4 under 8-dup layout
#define DPP_ROR8 0x128  // row_ror:8  == lane^8 within 16-row

template<int CTRL>
__device__ __forceinline__ float dppf(float v) {
    int r = __builtin_amdgcn_update_dpp(0, __builtin_bit_cast(int, v),
                                        CTRL, 0xF, 0xF, true);
    return __builtin_bit_cast(float, r);
}

__device__ __forceinline__ v2f mk2(float a, float b) { v2f v; v.x = a; v.y = b; return v; }

// act(x) = pA * sigmoid(-cpre_scaled x...) : e = exp2(x*cpre); s = 1/(1+e); pA*s+pB
//   sigmoid: cpre = -log2(e),    pA=1, pB=0
//   tanh:    cpre = -2 log2(e),  pA=2, pB=-1      (tanh(x) = 2*sigm(2x)-1)
__device__ __forceinline__ float actf(float x, float cpre, float pA, float pB) {
    float e = __builtin_amdgcn_exp2f(x * cpre);
    float s = __builtin_amdgcn_rcpf(1.0f + e);
    return __builtin_fmaf(pA, s, pB);
}

__global__ __launch_bounds__(256) void lstm2_dpp(
    const float* __restrict__ input,   // [NB, TT, 2]
    const float* __restrict__ w_ih0,   // [32, 2]
    const float* __restrict__ w_hh0,   // [32, 8]
    const float* __restrict__ b_ih0,   // [32]
    const float* __restrict__ b_hh0,   // [32]
    const float* __restrict__ w_ih1,   // [32, 8]
    const float* __restrict__ w_hh1,   // [32, 8]
    const float* __restrict__ b_ih1,   // [32]
    const float* __restrict__ b_hh1,   // [32]
    const float* __restrict__ w_mlp,   // [2, 8]
    const float* __restrict__ b_mlp,   // [2]
    float* __restrict__ out)           // [NB, 2]
{
    const int tid  = blockIdx.x * 256 + threadIdx.x;
    const int lane = threadIdx.x & 63;
    const int k    = lane & 7;
    const int rep  = (lane >> 3) & 1;
    const int elem = tid >> 4;          // 16 consecutive threads = one element = one DPP row

    const int rowA = rep ? 16 + k : k;       // i-row or g-row
    const int rowB = rep ? 24 + k : 8 + k;   // o-row or f-row... rep0:{i,f}, rep1:{g,o}

    // ---- register-resident, XOR-pre-permuted weights (loaded once) ----
    v2f wx0A = mk2(w_ih0[rowA*2+0], w_ih0[rowA*2+1]);
    v2f wx0B = mk2(w_ih0[rowB*2+0], w_ih0[rowB*2+1]);
    v2f wh0A[4], wh0B[4], wi1A[4], wi1B[4], wh1A[4], wh1B[4];
#pragma unroll
    for (int j = 0; j < 4; ++j) {
        const int i0 = k ^ (2*j), i1 = k ^ (2*j+1);
        wh0A[j] = mk2(w_hh0[rowA*8+i0], w_hh0[rowA*8+i1]);
        wh0B[j] = mk2(w_hh0[rowB*8+i0], w_hh0[rowB*8+i1]);
        wi1A[j] = mk2(w_ih1[rowA*8+i0], w_ih1[rowA*8+i1]);
        wi1B[j] = mk2(w_ih1[rowB*8+i0], w_ih1[rowB*8+i1]);
        wh1A[j] = mk2(w_hh1[rowA*8+i0], w_hh1[rowA*8+i1]);
        wh1B[j] = mk2(w_hh1[rowB*8+i0], w_hh1[rowB*8+i1]);
    }
    const float bA0 = b_ih0[rowA] + b_hh0[rowA];
    const float bB0 = b_ih0[rowB] + b_hh0[rowB];
    const float bA1 = b_ih1[rowA] + b_hh1[rowA];
    const float bB1 = b_ih1[rowB] + b_hh1[rowB];

    const float SIG   = -1.44269504088896f;       // -log2(e)
    const float cpreA = rep ? 2.0f*SIG : SIG;     // gate A: rep1 is tanh (g-gate)
    const float pAA   = rep ? 2.0f : 1.0f;
    const float pBA   = rep ? -1.0f : 0.0f;

    v2f h0p[4], h1p[4];
#pragma unroll
    for (int j = 0; j < 4; ++j) { h0p[j] = mk2(0.f, 0.f); h1p[j] = mk2(0.f, 0.f); }
    float c0 = 0.f, c1 = 0.f;

    const float4* __restrict__ xp =
        reinterpret_cast<const float4*>(input + (size_t)elem * (TT*2));

    auto rotate = [&](float h, v2f* hp) {
        float r1 = dppf<DPP_XOR1>(h);
        float r2 = dppf<DPP_XOR2>(h);
        float r3 = dppf<DPP_XOR3>(h);
        float r4 = dppf<DPP_ROR4>(h);
        float r5 = dppf<DPP_XOR1>(r4);
        float r6 = dppf<DPP_XOR2>(r4);
        float r7 = dppf<DPP_XOR3>(r4);
        hp[0] = mk2(h , r1); hp[1] = mk2(r2, r3);
        hp[2] = mk2(r4, r5); hp[3] = mk2(r6, r7);
    };

    auto lstm_step = [&](float x0, float x1) {
        // ---------------- layer 0 ----------------
        v2f x2 = mk2(x0, x1);
        v2f aA = mk2(bA0, 0.f), aB = mk2(bB0, 0.f);
        aA += wx0A * x2;  aB += wx0B * x2;
#pragma unroll
        for (int j = 0; j < 4; ++j) { aA += wh0A[j] * h0p[j]; aB += wh0B[j] * h0p[j]; }
        float a0 = actf(aA.x + aA.y, cpreA, pAA, pBA);   // rep0: i   rep1: g
        float a1 = actf(aB.x + aB.y, SIG, 1.0f, 0.0f);   // rep0: f   rep1: o
        float p0 = dppf<DPP_ROR8>(a0);
        float p1 = dppf<DPP_ROR8>(a1);
        float ig = rep ? p0 : a0;
        float fg = rep ? p1 : a1;
        float gg = rep ? a0 : p0;
        float og = rep ? a1 : p1;
        c0 = __builtin_fmaf(fg, c0, ig * gg);
        float h = og * actf(c0, 2.0f*SIG, 2.0f, -1.0f);
        rotate(h, h0p);
        // ---------------- layer 1 ----------------
        aA = mk2(bA1, 0.f);  aB = mk2(bB1, 0.f);
#pragma unroll
        for (int j = 0; j < 4; ++j) {
            aA += wi1A[j] * h0p[j];  aB += wi1B[j] * h0p[j];
            aA += wh1A[j] * h1p[j];  aB += wh1B[j] * h1p[j];
        }
        a0 = actf(aA.x + aA.y, cpreA, pAA, pBA);
        a1 = actf(aB.x + aB.y, SIG, 1.0f, 0.0f);
        p0 = dppf<DPP_ROR8>(a0);
        p1 = dppf<DPP_ROR8>(a1);
        ig = rep ? p0 : a0;
        fg = rep ? p1 : a1;
        gg = rep ? a0 : p0;
        og = rep ? a1 : p1;
        c1 = __builtin_fmaf(fg, c1, ig * gg);
        float hh = og * actf(c1, 2.0f*SIG, 2.0f, -1.0f);
        rotate(hh, h1p);
    };

    float4 cur = xp[0];
#pragma unroll 1
    for (int it = 0; it < TT/2; ++it) {
        float4 nxt = xp[(it + 1) & (TT/2 - 1)];   // wraps harmlessly on last iter
        lstm_step(cur.x, cur.y);
        lstm_step(cur.z, cur.w);
        cur = nxt;
    }

    // ---- MLP head: every lane holds all 8 h1 values in h1p pairs ----
    const int o = lane & 1;
    v2f wm[4];
#pragma unroll
    for (int j = 0; j < 4; ++j)
        wm[j] = mk2(w_mlp[o*8 + (k^(2*j))], w_mlp[o*8 + (k^(2*j+1))]);
    v2f acc = mk2(b_mlp[o], 0.f);
#pragma unroll
    for (int j = 0; j < 4; ++j) acc += wm[j] * h1p[j];
    if ((lane & 15) < 2)
        out[elem * 2 + o] = acc.x + acc.y;
}

extern "C" void kernel_launch(void* const* d_in, const int* in_sizes, int n_in,
                              void* d_out, int out_size, void* d_ws, size_t ws_size,
                              hipStream_t stream) {
    const float* input = (const float*)d_in[0];
    const float* w_ih0 = (const float*)d_in[1];
    const float* w_hh0 = (const float*)d_in[2];
    const float* b_ih0 = (const float*)d_in[3];
    const float* b_hh0 = (const float*)d_in[4];
    const float* w_ih1 = (const float*)d_in[5];
    const float* w_hh1 = (const float*)d_in[6];
    const float* b_ih1 = (const float*)d_in[7];
    const float* b_hh1 = (const float*)d_in[8];
    const float* w_mlp = (const float*)d_in[9];
    const float* b_mlp = (const float*)d_in[10];
    float* out = (float*)d_out;

    // 16 threads per batch element -> 32768*16 = 524288 threads
    dim3 block(256);
    dim3 grid((NB * 16) / 256);
    lstm2_dpp<<<grid, block, 0, stream>>>(input, w_ih0, w_hh0, b_ih0, b_hh0,
                                          w_ih1, w_hh1, b_ih1, b_hh1,
                                          w_mlp, b_mlp, out);
}

// Round 6
// 342.154 us; speedup vs baseline: 8.0734x; 1.3411x over previous
//
#include <hip/hip_runtime.h>

// LSTM_18210661335311 — R3 resubmit (R4/R5 were GPU-acquisition timeouts).
// MFMA design: one wave = 16 batch elements. Per timestep per layer:
// gates[32,16b] = W(fp16) x [x;h](fp16 hi+lo split) via 2x mfma_f32_16x16x32_f16
// (A=weight rows reordered [i,g | f,o], B cols = batch). C layout (m89):
// col=lane&15=batch, row=4*(lane>>4)+reg. shfl_xor(32) co-locates i,f,g,o;
// c/h fp32; h repacked fp16 hi(groups 0,1)/lo-residual(groups 2,3) per-lane,
// zero cross-lane traffic for B. Same (hi,j) k-slot convention for A and B.

#define TT 256
#define NB 32768

typedef _Float16 half_t;
typedef _Float16 v2h __attribute__((ext_vector_type(2)));
typedef _Float16 v8h __attribute__((ext_vector_type(8)));
typedef __fp16   q2h __attribute__((ext_vector_type(2)));
typedef float    v4f __attribute__((ext_vector_type(4)));

__device__ __forceinline__ v2h pkrtz(float a, float b) {
    q2h r = __builtin_amdgcn_cvt_pkrtz(a, b);
    return __builtin_bit_cast(v2h, r);
}

__device__ __forceinline__ float sigm(float x) {
    return __builtin_amdgcn_rcpf(1.0f + __builtin_amdgcn_exp2f(x * -1.44269504088896f));
}
__device__ __forceinline__ float tanh_(float x) {
    return __builtin_fmaf(2.0f,
        __builtin_amdgcn_rcpf(1.0f + __builtin_amdgcn_exp2f(x * -2.88539008177793f)), -1.0f);
}
__device__ __forceinline__ float actp(float x, float cpre, float pA, float pB) {
    return __builtin_fmaf(pA,
        __builtin_amdgcn_rcpf(1.0f + __builtin_amdgcn_exp2f(x * cpre)), pB);
}

__global__ __launch_bounds__(256) void lstm2_mfma(
    const float* __restrict__ input,   // [NB, TT, 2]
    const float* __restrict__ w_ih0,   // [32, 2]
    const float* __restrict__ w_hh0,   // [32, 8]
    const float* __restrict__ b_ih0,   // [32]
    const float* __restrict__ b_hh0,   // [32]
    const float* __restrict__ w_ih1,   // [32, 8]
    const float* __restrict__ w_hh1,   // [32, 8]
    const float* __restrict__ b_ih1,   // [32]
    const float* __restrict__ b_hh1,   // [32]
    const float* __restrict__ w_mlp,   // [2, 8]
    const float* __restrict__ b_mlp,   // [2]
    float* __restrict__ out)           // [NB, 2]
{
    const int  lane   = threadIdx.x & 63;
    const int  wave   = blockIdx.x * 4 + (threadIdx.x >> 6);
    const int  bcol   = lane & 15;        // batch column within the 16-tile
    const int  hi     = lane >> 4;        // k-slot group 0..3
    const bool hipart = (hi < 2);         // groups 0,1 supply fp16-hi, 2,3 lo
    const int  quad   = (hi & 1) * 4;     // this lane's hidden-quadrant offset
    const int  elem   = wave * 16 + bcol; // global batch element

    // ---- A fragments (weights, fp16, loaded once; lane supplies row ar) ----
    const int ar = lane & 15;
    const int g1 = (ar < 8) ? ar : 16 + (ar - 8);      // M1 rows: i[0..7], g[0..7]
    const int g2 = (ar < 8) ? 8 + ar : 24 + (ar - 8);  // M2 rows: f[0..7], o[0..7]

    v8h A0a, A0b, A1a, A1b;
    {
        const bool xg = ((hi & 1) == 0);  // only quad-0 groups carry x slots
        A0a[0] = xg ? (half_t)w_ih0[g1 * 2 + 0] : (half_t)0.f;
        A0a[1] = xg ? (half_t)w_ih0[g1 * 2 + 1] : (half_t)0.f;
        A0b[0] = xg ? (half_t)w_ih0[g2 * 2 + 0] : (half_t)0.f;
        A0b[1] = xg ? (half_t)w_ih0[g2 * 2 + 1] : (half_t)0.f;
#pragma unroll
        for (int j = 0; j < 4; ++j) {
            A0a[2 + j] = (half_t)w_hh0[g1 * 8 + quad + j];
            A0b[2 + j] = (half_t)w_hh0[g2 * 8 + quad + j];
            A1a[j]     = (half_t)w_ih1[g1 * 8 + quad + j];
            A1a[4 + j] = (half_t)w_hh1[g1 * 8 + quad + j];
            A1b[j]     = (half_t)w_ih1[g2 * 8 + quad + j];
            A1b[4 + j] = (half_t)w_hh1[g2 * 8 + quad + j];
        }
        A0a[6] = A0a[7] = (half_t)0.f;
        A0b[6] = A0b[7] = (half_t)0.f;
    }

    // ---- bias as C-init (C row m = 4*hi + reg) ----
    v4f bias0a, bias0b, bias1a, bias1b;
#pragma unroll
    for (int q = 0; q < 4; ++q) {
        const int m  = 4 * hi + q;
        const int p1 = (m < 8) ? m : 16 + (m - 8);
        const int p2 = (m < 8) ? 8 + m : 24 + (m - 8);
        bias0a[q] = b_ih0[p1] + b_hh0[p1];
        bias0b[q] = b_ih0[p2] + b_hh0[p2];
        bias1a[q] = b_ih1[p1] + b_hh1[p1];
        bias1b[q] = b_ih1[p2] + b_hh1[p2];
    }

    // act params for M1 values: i (sigmoid) at hi<2, g (tanh) at hi>=2
    const float L2E   = 1.44269504088896f;
    const float cpreA = hipart ? -L2E : -2.0f * L2E;
    const float pAA   = hipart ? 1.0f : 2.0f;
    const float pBA   = hipart ? 0.0f : -1.0f;

    // pack own h-quadrant to fp16: hi groups take RTZ hi-part, lo groups residual
    auto packsel = [&](v4f h, v2h& a, v2h& b) {
        v2h ha = pkrtz(h.x, h.y);
        v2h hb = pkrtz(h.z, h.w);
        v2h la = pkrtz(h.x - (float)ha.x, h.y - (float)ha.y);
        v2h lb = pkrtz(h.z - (float)hb.x, h.w - (float)hb.y);
        a = hipart ? ha : la;
        b = hipart ? hb : lb;
    };

    v2h h0a = {(half_t)0.f, (half_t)0.f}, h0b = h0a, h1a = h0a, h1b = h0a;
    v4f c0 = {0.f, 0.f, 0.f, 0.f}, c1 = c0;
    v4f h1q = c0;  // layer-1 h in fp32 (for MLP head)

    const float4* __restrict__ xp =
        reinterpret_cast<const float4*>(input + (size_t)elem * (TT * 2));

    auto cell = [&](float x0, float x1) {
        // x hi+lo split (effectively exact)
        v2h xh = pkrtz(x0, x1);
        v2h xl = pkrtz(x0 - (float)xh.x, x1 - (float)xh.y);
        v2h xs = hipart ? xh : xl;

        // ---------------- layer 0 ----------------
        v8h B0;
        B0[0] = xs.x;  B0[1] = xs.y;
        B0[2] = h0a.x; B0[3] = h0a.y; B0[4] = h0b.x; B0[5] = h0b.y;
        B0[6] = (half_t)0.f; B0[7] = (half_t)0.f;
        v4f ac1 = __builtin_amdgcn_mfma_f32_16x16x32_f16(A0a, B0, bias0a, 0, 0, 0);
        v4f ac2 = __builtin_amdgcn_mfma_f32_16x16x32_f16(A0b, B0, bias0b, 0, 0, 0);

        v4f oa, ob, ga, gb;
#pragma unroll
        for (int j = 0; j < 4; ++j) {
            oa[j] = actp(ac1[j], cpreA, pAA, pBA);  // i (hi<2) or g (hi>=2)
            ob[j] = sigm(ac2[j]);                   // f (hi<2) or o (hi>=2)
        }
#pragma unroll
        for (int j = 0; j < 4; ++j) {
            ga[j] = __shfl_xor(oa[j], 32);
            gb[j] = __shfl_xor(ob[j], 32);
        }
        v4f fv = hipart ? ob : gb;
        v4f ov = hipart ? gb : ob;
        v4f th;
#pragma unroll
        for (int j = 0; j < 4; ++j) {
            c0[j] = __builtin_fmaf(fv[j], c0[j], oa[j] * ga[j]);  // i*g = oa*ga both ways
            th[j] = tanh_(c0[j]);
        }
        v4f h0 = ov * th;
        packsel(h0, h0a, h0b);

        // ---------------- layer 1 ----------------
        v8h B1;
        B1[0] = h0a.x; B1[1] = h0a.y; B1[2] = h0b.x; B1[3] = h0b.y;
        B1[4] = h1a.x; B1[5] = h1a.y; B1[6] = h1b.x; B1[7] = h1b.y;
        ac1 = __builtin_amdgcn_mfma_f32_16x16x32_f16(A1a, B1, bias1a, 0, 0, 0);
        ac2 = __builtin_amdgcn_mfma_f32_16x16x32_f16(A1b, B1, bias1b, 0, 0, 0);

#pragma unroll
        for (int j = 0; j < 4; ++j) {
            oa[j] = actp(ac1[j], cpreA, pAA, pBA);
            ob[j] = sigm(ac2[j]);
        }
#pragma unroll
        for (int j = 0; j < 4; ++j) {
            ga[j] = __shfl_xor(oa[j], 32);
            gb[j] = __shfl_xor(ob[j], 32);
        }
        fv = hipart ? ob : gb;
        ov = hipart ? gb : ob;
#pragma unroll
        for (int j = 0; j < 4; ++j) {
            c1[j] = __builtin_fmaf(fv[j], c1[j], oa[j] * ga[j]);
            th[j] = tanh_(c1[j]);
        }
        h1q = ov * th;
        packsel(h1q, h1a, h1b);
    };

    float4 cur = xp[0];
#pragma unroll 1
    for (int it = 0; it < TT / 2; ++it) {
        float4 nxt = xp[(it + 1) & (TT / 2 - 1)];  // harmless wrap on last iter
        cell(cur.x, cur.y);
        cell(cur.z, cur.w);
        cur = nxt;
    }

    // ---- MLP head: lane holds h1[quad..quad+3]; sum quads via shfl_xor(16) ----
    float p0 = 0.f, p1 = 0.f;
#pragma unroll
    for (int j = 0; j < 4; ++j) {
        p0 += w_mlp[0 * 8 + quad + j] * h1q[j];
        p1 += w_mlp[1 * 8 + quad + j] * h1q[j];
    }
    p0 += __shfl_xor(p0, 16);
    p1 += __shfl_xor(p1, 16);
    if (hi == 0) {
        out[elem * 2 + 0] = p0 + b_mlp[0];
        out[elem * 2 + 1] = p1 + b_mlp[1];
    }
}

extern "C" void kernel_launch(void* const* d_in, const int* in_sizes, int n_in,
                              void* d_out, int out_size, void* d_ws, size_t ws_size,
                              hipStream_t stream) {
    const float* input = (const float*)d_in[0];
    const float* w_ih0 = (const float*)d_in[1];
    const float* w_hh0 = (const float*)d_in[2];
    const float* b_ih0 = (const float*)d_in[3];
    const float* b_hh0 = (const float*)d_in[4];
    const float* w_ih1 = (const float*)d_in[5];
    const float* w_hh1 = (const float*)d_in[6];
    const float* b_ih1 = (const float*)d_in[7];
    const float* b_hh1 = (const float*)d_in[8];
    const float* w_mlp = (const float*)d_in[9];
    const float* b_mlp = (const float*)d_in[10];
    float* out = (float*)d_out;

    // one wave per 16 batch elements: 2048 waves, 4 waves (256 thr) per block
    dim3 block(256);
    dim3 grid(NB / 64);
    lstm2_mfma<<<grid, block, 0, stream>>>(input, w_ih0, w_hh0, b_ih0, b_hh0,
                                           w_ih1, w_hh1, b_ih1, b_hh1,
                                           w_mlp, b_mlp, out);
}

// Round 7
// 262.429 us; speedup vs baseline: 10.5260x; 1.3038x over previous
//
#include <hip/hip_runtime.h>

// LSTM_18210661335311 — R7: 32x32x16 MFMA, one wave = 32 batch elements.
// C layout (m74/m101): col=lane&31, row=(reg&3)+8*(reg>>2)+4*(lane>>5).
// Row stride 8 across reg-quads == PyTorch gate stride, so each lane holds
// i,f,g,o for hidden q..q+3 (q=4*(lane>>5)) of ONE batch col — no gate
// shuffles/selects. One MFMA per layer per step. Activation pre-scales
// (-log2e sigmoid rows, -2log2e tanh rows) folded into A and bias C-init.
// h carried fp16 (RTN); x hi+lo split in idle k-slots (exact). Cross-lane:
// 4 packed shfl_xor(32) per cell (h half-exchange). 1024 waves (1/SIMD).

#define TT 256
#define NB 32768

typedef _Float16 half_t;
typedef _Float16 v2h  __attribute__((ext_vector_type(2)));
typedef _Float16 v8h  __attribute__((ext_vector_type(8)));
typedef __fp16   q2h  __attribute__((ext_vector_type(2)));
typedef float    v16f __attribute__((ext_vector_type(16)));
typedef int      v4i  __attribute__((ext_vector_type(4)));

__device__ __forceinline__ v2h pkrtz(float a, float b) {
    q2h r = __builtin_amdgcn_cvt_pkrtz(a, b);
    return __builtin_bit_cast(v2h, r);
}
// RTN pack (v_cvt_f16_f32 is round-to-nearest; unbiased for the recurrence)
__device__ __forceinline__ int pk_rtn(float a, float b) {
    v2h v; v.x = (half_t)a; v.y = (half_t)b;
    return __builtin_bit_cast(int, v);
}
__device__ __forceinline__ float rcp_(float x) { return __builtin_amdgcn_rcpf(x); }
__device__ __forceinline__ float ex2_(float x) { return __builtin_amdgcn_exp2f(x); }

__global__ __launch_bounds__(256) void lstm2_mfma32(
    const float* __restrict__ input,   // [NB, TT, 2]
    const float* __restrict__ w_ih0,   // [32, 2]
    const float* __restrict__ w_hh0,   // [32, 8]
    const float* __restrict__ b_ih0,   // [32]
    const float* __restrict__ b_hh0,   // [32]
    const float* __restrict__ w_ih1,   // [32, 8]
    const float* __restrict__ w_hh1,   // [32, 8]
    const float* __restrict__ b_ih1,   // [32]
    const float* __restrict__ b_hh1,   // [32]
    const float* __restrict__ w_mlp,   // [2, 8]
    const float* __restrict__ b_mlp,   // [2]
    float* __restrict__ out)           // [NB, 2]
{
    const int lane = threadIdx.x & 63;
    const int wave = blockIdx.x * 4 + (threadIdx.x >> 6);
    const int col  = lane & 31;        // batch column = A row index
    const int hf   = lane >> 5;        // k-group / hidden-half
    const int elem = wave * 32 + col;

    const float L2E = 1.44269504088896f;
    const float NS  = -L2E;            // sigmoid pre-scale
    const float NT2 = -2.0f * L2E;     // tanh pre-scale

    // ---- A fragments: row=col, k=8*hf+j; per-row act scale folded in ----
    const int   row = col;
    const float sA  = (row >= 16 && row < 24) ? NT2 : NS;   // g-rows are tanh

    v8h A0, A1;
    if (hf == 0) {
        // k0-7: layer0 = w_hh0 (h slots); layer1 = w_ih1 (h0 slots)
#pragma unroll
        for (int j = 0; j < 8; ++j) {
            A0[j] = (half_t)(sA * w_hh0[row * 8 + j]);
            A1[j] = (half_t)(sA * w_ih1[row * 8 + j]);
        }
    } else {
        // k8-15: layer0 = x_hi(2) + x_lo(2) + zeros; layer1 = w_hh1 (h1 slots)
        A0[0] = (half_t)(sA * w_ih0[row * 2 + 0]);
        A0[1] = (half_t)(sA * w_ih0[row * 2 + 1]);
        A0[2] = A0[0];
        A0[3] = A0[1];
#pragma unroll
        for (int j = 4; j < 8; ++j) A0[j] = (half_t)0.f;
#pragma unroll
        for (int j = 0; j < 8; ++j) A1[j] = (half_t)(sA * w_hh1[row * 8 + j]);
    }

    // ---- bias C-init (scaled), reg r -> row (r&3)+8*(r>>2)+4*hf ----
    v16f bias0, bias1;
#pragma unroll
    for (int r = 0; r < 16; ++r) {
        const int   rw = (r & 3) + 8 * (r >> 2) + 4 * hf;
        const float s  = (rw >= 16 && rw < 24) ? NT2 : NS;
        bias0[r] = s * (b_ih0[rw] + b_hh0[rw]);
        bias1[r] = s * (b_ih1[rw] + b_hh1[rw]);
    }

    float c0[4] = {0.f, 0.f, 0.f, 0.f}, c1[4] = {0.f, 0.f, 0.f, 0.f};
    // full h0[0-7] / h1[0-7] as 4 packed-f16 words each
    int h0w0 = 0, h0w1 = 0, h0w2 = 0, h0w3 = 0;
    int h1w0 = 0, h1w1 = 0, h1w2 = 0, h1w3 = 0;
    float h1f[4] = {0.f, 0.f, 0.f, 0.f};   // own h1 quad in f32 (MLP head)

    const float4* __restrict__ xp =
        reinterpret_cast<const float4*>(input + (size_t)elem * (TT * 2));

    auto cell = [&](float x0, float x1) {
        v2h xh = pkrtz(x0, x1);
        v2h xl = pkrtz(x0 - (float)xh.x, x1 - (float)xh.y);
        const int xw0 = __builtin_bit_cast(int, xh);
        const int xw1 = __builtin_bit_cast(int, xl);

        // ---------------- layer 0 ----------------
        v4i b;
        b.x = hf ? xw0 : h0w0;
        b.y = hf ? xw1 : h0w1;
        b.z = hf ? 0   : h0w2;
        b.w = hf ? 0   : h0w3;
        v16f acc = __builtin_amdgcn_mfma_f32_32x32x16_f16(
            A0, __builtin_bit_cast(v8h, b), bias0, 0, 0, 0);

        float nh[4];
#pragma unroll
        for (int j = 0; j < 4; ++j) {
            float ig = rcp_(1.f + ex2_(acc[j]));                           // i
            float fg = rcp_(1.f + ex2_(acc[4 + j]));                       // f
            float gg = __builtin_fmaf(2.f, rcp_(1.f + ex2_(acc[8 + j])), -1.f);  // g
            float og = rcp_(1.f + ex2_(acc[12 + j]));                      // o
            c0[j] = __builtin_fmaf(fg, c0[j], ig * gg);
            float t = __builtin_fmaf(2.f, rcp_(1.f + ex2_(c0[j] * NT2)), -1.f);
            nh[j] = og * t;
        }
        {
            int own0 = pk_rtn(nh[0], nh[1]);
            int own1 = pk_rtn(nh[2], nh[3]);
            int oth0 = __shfl_xor(own0, 32);
            int oth1 = __shfl_xor(own1, 32);
            h0w0 = hf ? oth0 : own0;
            h0w1 = hf ? oth1 : own1;
            h0w2 = hf ? own0 : oth0;
            h0w3 = hf ? own1 : oth1;
        }

        // ---------------- layer 1 ----------------
        b.x = hf ? h1w0 : h0w0;     // group0 supplies h0[0-7], group1 h1[0-7]
        b.y = hf ? h1w1 : h0w1;
        b.z = hf ? h1w2 : h0w2;
        b.w = hf ? h1w3 : h0w3;
        acc = __builtin_amdgcn_mfma_f32_32x32x16_f16(
            A1, __builtin_bit_cast(v8h, b), bias1, 0, 0, 0);

#pragma unroll
        for (int j = 0; j < 4; ++j) {
            float ig = rcp_(1.f + ex2_(acc[j]));
            float fg = rcp_(1.f + ex2_(acc[4 + j]));
            float gg = __builtin_fmaf(2.f, rcp_(1.f + ex2_(acc[8 + j])), -1.f);
            float og = rcp_(1.f + ex2_(acc[12 + j]));
            c1[j] = __builtin_fmaf(fg, c1[j], ig * gg);
            float t = __builtin_fmaf(2.f, rcp_(1.f + ex2_(c1[j] * NT2)), -1.f);
            h1f[j] = og * t;
        }
        {
            int own0 = pk_rtn(h1f[0], h1f[1]);
            int own1 = pk_rtn(h1f[2], h1f[3]);
            int oth0 = __shfl_xor(own0, 32);
            int oth1 = __shfl_xor(own1, 32);
            h1w0 = hf ? oth0 : own0;
            h1w1 = hf ? oth1 : own1;
            h1w2 = hf ? own0 : oth0;
            h1w3 = hf ? own1 : oth1;
        }
    };

    float4 cur = xp[0];
#pragma unroll 1
    for (int it = 0; it < TT / 2; ++it) {
        float4 nxt = xp[(it + 1) & (TT / 2 - 1)];  // harmless wrap on last iter
        cell(cur.x, cur.y);
        cell(cur.z, cur.w);
        cur = nxt;
    }

    // ---- MLP head: own quad (q..q+3) partial, xor(32) completes the dot ----
    const int q = 4 * hf;
    float p0 = 0.f, p1 = 0.f;
#pragma unroll
    for (int j = 0; j < 4; ++j) {
        p0 += w_mlp[q + j] * h1f[j];
        p1 += w_mlp[8 + q + j] * h1f[j];
    }
    p0 += __shfl_xor(p0, 32);
    p1 += __shfl_xor(p1, 32);
    if (hf == 0) {
        out[elem * 2 + 0] = p0 + b_mlp[0];
        out[elem * 2 + 1] = p1 + b_mlp[1];
    }
}

extern "C" void kernel_launch(void* const* d_in, const int* in_sizes, int n_in,
                              void* d_out, int out_size, void* d_ws, size_t ws_size,
                              hipStream_t stream) {
    const float* input = (const float*)d_in[0];
    const float* w_ih0 = (const float*)d_in[1];
    const float* w_hh0 = (const float*)d_in[2];
    const float* b_ih0 = (const float*)d_in[3];
    const float* b_hh0 = (const float*)d_in[4];
    const float* w_ih1 = (const float*)d_in[5];
    const float* w_hh1 = (const float*)d_in[6];
    const float* b_ih1 = (const float*)d_in[7];
    const float* b_hh1 = (const float*)d_in[8];
    const float* w_mlp = (const float*)d_in[9];
    const float* b_mlp = (const float*)d_in[10];
    float* out = (float*)d_out;

    // one wave per 32 batch elements: 1024 waves, 4 waves (256 thr) per block
    dim3 block(256);
    dim3 grid(NB / 128);
    lstm2_mfma32<<<grid, block, 0, stream>>>(input, w_ih0, w_hh0, b_ih0, b_hh0,
                                             w_ih1, w_hh1, b_ih1, b_hh1,
                                             w_mlp, b_mlp, out);
}

// Round 8
// 256.627 us; speedup vs baseline: 10.7640x; 1.0226x over previous
//
#include <hip/hip_runtime.h>

// LSTM_18210661335311 — R8: layer-pipelined 32x32x16 MFMA.
// Block = 256 thr = 4 waves = 2 elem-groups x {layer0 producer, layer1 consumer}.
// Producer streams h0 (packed fp16, 4 words/elem) through double-buffered LDS
// chunks of CH=16 steps; consumer runs one chunk behind. 2048 waves = 2/SIMD
// (vs R7's 1), filling the ~33% dependency-stall window seen at VALUBusy=67%.
// Cell math identical to R7: C layout row=(reg&3)+8*(reg>>2)+4*(lane>>5) ==
// PyTorch gate stride 8, act pre-scales folded into A/bias, h fp16 RTN,
// x hi+lo split exact.

#define TT  256
#define NB  32768
#define CH  16
#define NCH (TT / CH)

typedef _Float16 half_t;
typedef _Float16 v2h  __attribute__((ext_vector_type(2)));
typedef _Float16 v8h  __attribute__((ext_vector_type(8)));
typedef __fp16   q2h  __attribute__((ext_vector_type(2)));
typedef float    v16f __attribute__((ext_vector_type(16)));
typedef int      v4i  __attribute__((ext_vector_type(4)));

__device__ __forceinline__ v2h pkrtz(float a, float b) {
    q2h r = __builtin_amdgcn_cvt_pkrtz(a, b);
    return __builtin_bit_cast(v2h, r);
}
__device__ __forceinline__ int pk_rtn(float a, float b) {
    v2h v; v.x = (half_t)a; v.y = (half_t)b;
    return __builtin_bit_cast(int, v);
}
__device__ __forceinline__ float rcp_(float x) { return __builtin_amdgcn_rcpf(x); }
__device__ __forceinline__ float ex2_(float x) { return __builtin_amdgcn_exp2f(x); }

__global__ __launch_bounds__(256) void lstm2_pipe(
    const float* __restrict__ input,   // [NB, TT, 2]
    const float* __restrict__ w_ih0,   // [32, 2]
    const float* __restrict__ w_hh0,   // [32, 8]
    const float* __restrict__ b_ih0,   // [32]
    const float* __restrict__ b_hh0,   // [32]
    const float* __restrict__ w_ih1,   // [32, 8]
    const float* __restrict__ w_hh1,   // [32, 8]
    const float* __restrict__ b_ih1,   // [32]
    const float* __restrict__ b_hh1,   // [32]
    const float* __restrict__ w_mlp,   // [2, 8]
    const float* __restrict__ b_mlp,   // [2]
    float* __restrict__ out)           // [NB, 2]
{
    const int lane = threadIdx.x & 63;
    const int wv   = threadIdx.x >> 6;   // 0..3
    const int grp  = wv & 1;             // elem-group within block
    const int role = wv >> 1;            // 0: layer0 producer, 1: layer1 consumer
    const int col  = lane & 31;
    const int hf   = lane >> 5;
    const int elem = blockIdx.x * 64 + grp * 32 + col;

    // [grp][dbuf][step][col*4 + word]  = 32 KB
    __shared__ int h0buf[2][2][CH][128];

    const float L2E = 1.44269504088896f;
    const float NS  = -L2E;
    const float NT2 = -2.0f * L2E;
    const float sA  = (col >= 16 && col < 24) ? NT2 : NS;   // g-rows tanh

    // ---- A fragment (act scale folded), role-specific ----
    v8h A;
    if (role == 0) {
        if (hf == 0) {
#pragma unroll
            for (int j = 0; j < 8; ++j) A[j] = (half_t)(sA * w_hh0[col * 8 + j]);
        } else {
            A[0] = (half_t)(sA * w_ih0[col * 2 + 0]);
            A[1] = (half_t)(sA * w_ih0[col * 2 + 1]);
            A[2] = A[0]; A[3] = A[1];
#pragma unroll
            for (int j = 4; j < 8; ++j) A[j] = (half_t)0.f;
        }
    } else {
        const float* wsrc = hf ? w_hh1 : w_ih1;
#pragma unroll
        for (int j = 0; j < 8; ++j) A[j] = (half_t)(sA * wsrc[col * 8 + j]);
    }

    // ---- bias C-init (scaled) ----
    v16f bias;
#pragma unroll
    for (int r = 0; r < 16; ++r) {
        const int   rw = (r & 3) + 8 * (r >> 2) + 4 * hf;
        const float s  = (rw >= 16 && rw < 24) ? NT2 : NS;
        bias[r] = (role == 0) ? s * (b_ih0[rw] + b_hh0[rw])
                              : s * (b_ih1[rw] + b_hh1[rw]);
    }

    float c[4] = {0.f, 0.f, 0.f, 0.f};
    int   hw0 = 0, hw1 = 0, hw2 = 0, hw3 = 0;  // full own-layer h, packed fp16
    float hq[4] = {0.f, 0.f, 0.f, 0.f};        // consumer: own h1 quad (f32)

    const float4* __restrict__ xp =
        reinterpret_cast<const float4*>(input + (size_t)elem * (TT * 2));

    auto gates = [&](const v16f& acc, float* hout) {
#pragma unroll
        for (int j = 0; j < 4; ++j) {
            float ig = rcp_(1.f + ex2_(acc[j]));
            float fg = rcp_(1.f + ex2_(acc[4 + j]));
            float gg = __builtin_fmaf(2.f, rcp_(1.f + ex2_(acc[8 + j])), -1.f);
            float og = rcp_(1.f + ex2_(acc[12 + j]));
            c[j] = __builtin_fmaf(fg, c[j], ig * gg);
            float t = __builtin_fmaf(2.f, rcp_(1.f + ex2_(c[j] * NT2)), -1.f);
            hout[j] = og * t;
        }
    };

    for (int ph = 0; ph <= NCH; ++ph) {
        if (role == 0) {
            if (ph < NCH) {
                int* lb = &h0buf[grp][ph & 1][0][0];
#pragma unroll 2
                for (int s2 = 0; s2 < CH / 2; ++s2) {
                    float4 xv = xp[ph * (CH / 2) + s2];
#pragma unroll
                    for (int half = 0; half < 2; ++half) {
                        float x0 = half ? xv.z : xv.x;
                        float x1 = half ? xv.w : xv.y;
                        v2h xh = pkrtz(x0, x1);
                        v2h xl = pkrtz(x0 - (float)xh.x, x1 - (float)xh.y);
                        int xw0 = __builtin_bit_cast(int, xh);
                        int xw1 = __builtin_bit_cast(int, xl);
                        v4i b;
                        b.x = hf ? xw0 : hw0;
                        b.y = hf ? xw1 : hw1;
                        b.z = hf ? 0   : hw2;
                        b.w = hf ? 0   : hw3;
                        v16f acc = __builtin_amdgcn_mfma_f32_32x32x16_f16(
                            A, __builtin_bit_cast(v8h, b), bias, 0, 0, 0);
                        float nh[4];
                        gates(acc, nh);
                        int own0 = pk_rtn(nh[0], nh[1]);
                        int own1 = pk_rtn(nh[2], nh[3]);
                        int2 st; st.x = own0; st.y = own1;
                        *reinterpret_cast<int2*>(
                            &lb[(2 * s2 + half) * 128 + col * 4 + hf * 2]) = st;
                        int oth0 = __shfl_xor(own0, 32);
                        int oth1 = __shfl_xor(own1, 32);
                        hw0 = hf ? oth0 : own0;
                        hw1 = hf ? oth1 : own1;
                        hw2 = hf ? own0 : oth0;
                        hw3 = hf ? own1 : oth1;
                    }
                }
            }
        } else if (ph > 0) {
            const int* lb = &h0buf[grp][(ph - 1) & 1][0][0];
#pragma unroll 2
            for (int s = 0; s < CH; ++s) {
                v4i hh = *reinterpret_cast<const v4i*>(&lb[s * 128 + col * 4]);
                v4i b;
                b.x = hf ? hw0 : hh.x;
                b.y = hf ? hw1 : hh.y;
                b.z = hf ? hw2 : hh.z;
                b.w = hf ? hw3 : hh.w;
                v16f acc = __builtin_amdgcn_mfma_f32_32x32x16_f16(
                    A, __builtin_bit_cast(v8h, b), bias, 0, 0, 0);
                gates(acc, hq);
                int own0 = pk_rtn(hq[0], hq[1]);
                int own1 = pk_rtn(hq[2], hq[3]);
                int oth0 = __shfl_xor(own0, 32);
                int oth1 = __shfl_xor(own1, 32);
                hw0 = hf ? oth0 : own0;
                hw1 = hf ? oth1 : own1;
                hw2 = hf ? own0 : oth0;
                hw3 = hf ? own1 : oth1;
            }
        }
        __syncthreads();
    }

    // ---- MLP head (consumer waves only) ----
    if (role == 1) {
        const int q = 4 * hf;
        float p0 = 0.f, p1 = 0.f;
#pragma unroll
        for (int j = 0; j < 4; ++j) {
            p0 += w_mlp[q + j] * hq[j];
            p1 += w_mlp[8 + q + j] * hq[j];
        }
        p0 += __shfl_xor(p0, 32);
        p1 += __shfl_xor(p1, 32);
        if (hf == 0) {
            out[elem * 2 + 0] = p0 + b_mlp[0];
            out[elem * 2 + 1] = p1 + b_mlp[1];
        }
    }
}

extern "C" void kernel_launch(void* const* d_in, const int* in_sizes, int n_in,
                              void* d_out, int out_size, void* d_ws, size_t ws_size,
                              hipStream_t stream) {
    const float* input = (const float*)d_in[0];
    const float* w_ih0 = (const float*)d_in[1];
    const float* w_hh0 = (const float*)d_in[2];
    const float* b_ih0 = (const float*)d_in[3];
    const float* b_hh0 = (const float*)d_in[4];
    const float* w_ih1 = (const float*)d_in[5];
    const float* w_hh1 = (const float*)d_in[6];
    const float* b_ih1 = (const float*)d_in[7];
    const float* b_hh1 = (const float*)d_in[8];
    const float* w_mlp = (const float*)d_in[9];
    const float* b_mlp = (const float*)d_in[10];
    float* out = (float*)d_out;

    // 64 elems per block (2 groups x 32), 4 waves per block -> 2048 waves
    dim3 block(256);
    dim3 grid(NB / 64);
    lstm2_pipe<<<grid, block, 0, stream>>>(input, w_ih0, w_hh0, b_ih0, b_hh0,
                                           w_ih1, w_hh1, b_ih1, b_hh1,
                                           w_mlp, b_mlp, out);
}

// Round 13
// 240.786 us; speedup vs baseline: 11.4721x; 1.0658x over previous
//
#include <hip/hip_runtime.h>

// LSTM_18210661335311 — R9 resubmit #4 (R9-R12 benches were GPU-acquisition
// timeouts). Shuffle-free MFMA + layer-dual-issue.
// One wave = 32 batch elements, 32x32x16 MFMA (C row = (reg&3)+8*(reg>>2)+4*hf
// == PyTorch gate stride 8 -> lane holds i,f,g,o for its hidden quad).
// NO cross-lane h exchange: each lane-half feeds its OWN h-quad into its own
// k-slots; the MFMA reduces across the wave. B0={h0own,x(hi,lo)} and
// B1={h0own,h1own} are lane-uniform register patterns; A encodes the mapping:
//   A0 (hf=0): [whh0[r,0-3] | wih0[r,0],wih0[r,1] (x_hi), same (x_lo)]
//   A0 (hf=1): [whh0[r,4-7] | 0,0,0,0]              (x counted once, in hf=0)
//   A1        : [wih1[r,4hf+j] | whh1[r,4hf+j]]
// Time loop dual-issues L0(t+1) and L1(t): both depend only on h0(t)/h1(t-1),
// so 2 MFMAs issue back-to-back and 2 act blocks interleave (8 indep chains).
// Act pre-scales folded into A/bias; h fp16 RTN; x hi+lo split exact.

#define TT 256
#define NB 32768

typedef _Float16 half_t;
typedef _Float16 v2h  __attribute__((ext_vector_type(2)));
typedef _Float16 v8h  __attribute__((ext_vector_type(8)));
typedef __fp16   q2h  __attribute__((ext_vector_type(2)));
typedef float    v16f __attribute__((ext_vector_type(16)));
typedef int      v4i  __attribute__((ext_vector_type(4)));

__device__ __forceinline__ v2h pkrtz(float a, float b) {
    q2h r = __builtin_amdgcn_cvt_pkrtz(a, b);
    return __builtin_bit_cast(v2h, r);
}
__device__ __forceinline__ int pk_rtn(float a, float b) {
    v2h v; v.x = (half_t)a; v.y = (half_t)b;
    return __builtin_bit_cast(int, v);
}
__device__ __forceinline__ float rcp_(float x) { return __builtin_amdgcn_rcpf(x); }
__device__ __forceinline__ float ex2_(float x) { return __builtin_amdgcn_exp2f(x); }

__global__ __launch_bounds__(256) void lstm2_dual(
    const float* __restrict__ input,   // [NB, TT, 2]
    const float* __restrict__ w_ih0,   // [32, 2]
    const float* __restrict__ w_hh0,   // [32, 8]
    const float* __restrict__ b_ih0,   // [32]
    const float* __restrict__ b_hh0,   // [32]
    const float* __restrict__ w_ih1,   // [32, 8]
    const float* __restrict__ w_hh1,   // [32, 8]
    const float* __restrict__ b_ih1,   // [32]
    const float* __restrict__ b_hh1,   // [32]
    const float* __restrict__ w_mlp,   // [2, 8]
    const float* __restrict__ b_mlp,   // [2]
    float* __restrict__ out)           // [NB, 2]
{
    const int lane = threadIdx.x & 63;
    const int wave = blockIdx.x * 4 + (threadIdx.x >> 6);
    const int col  = lane & 31;        // batch column = A row index
    const int hf   = lane >> 5;        // k-half / hidden-half
    const int elem = wave * 32 + col;

    const float L2E = 1.44269504088896f;
    const float NS  = -L2E;
    const float NT2 = -2.0f * L2E;
    const int   row = col;
    const float sA  = (row >= 16 && row < 24) ? NT2 : NS;   // g-rows tanh

    // ---- A fragments (act scale folded) ----
    v8h A0, A1;
#pragma unroll
    for (int j = 0; j < 4; ++j) {
        A0[j]     = (half_t)(sA * w_hh0[row * 8 + 4 * hf + j]);
        A1[j]     = (half_t)(sA * w_ih1[row * 8 + 4 * hf + j]);
        A1[4 + j] = (half_t)(sA * w_hh1[row * 8 + 4 * hf + j]);
    }
    if (hf == 0) {
        A0[4] = (half_t)(sA * w_ih0[row * 2 + 0]);
        A0[5] = (half_t)(sA * w_ih0[row * 2 + 1]);
        A0[6] = A0[4]; A0[7] = A0[5];
    } else {
        A0[4] = A0[5] = A0[6] = A0[7] = (half_t)0.f;
    }

    // ---- bias C-init (scaled); reg r -> row (r&3)+8*(r>>2)+4*hf ----
    v16f bias0, bias1;
#pragma unroll
    for (int r = 0; r < 16; ++r) {
        const int   rw = (r & 3) + 8 * (r >> 2) + 4 * hf;
        const float s  = (rw >= 16 && rw < 24) ? NT2 : NS;
        bias0[r] = s * (b_ih0[rw] + b_hh0[rw]);
        bias1[r] = s * (b_ih1[rw] + b_hh1[rw]);
    }

    float c0[4] = {0.f, 0.f, 0.f, 0.f}, c1[4] = {0.f, 0.f, 0.f, 0.f};
    int   h0w0 = 0, h0w1 = 0;          // own h0 quad, packed fp16
    int   h1w0 = 0, h1w1 = 0;          // own h1 quad, packed fp16
    float h1f[4] = {0.f, 0.f, 0.f, 0.f};

    const float4* __restrict__ xp =
        reinterpret_cast<const float4*>(input + (size_t)elem * (TT * 2));

    auto gates = [&](const v16f& acc, float* c, float* hout) {
#pragma unroll
        for (int j = 0; j < 4; ++j) {
            float ig = rcp_(1.f + ex2_(acc[j]));
            float fg = rcp_(1.f + ex2_(acc[4 + j]));
            float gg = __builtin_fmaf(2.f, rcp_(1.f + ex2_(acc[8 + j])), -1.f);
            float og = rcp_(1.f + ex2_(acc[12 + j]));
            c[j] = __builtin_fmaf(fg, c[j], ig * gg);
            float t = __builtin_fmaf(2.f, rcp_(1.f + ex2_(c[j] * NT2)), -1.f);
            hout[j] = og * t;
        }
    };

    auto packx = [&](float x0, float x1) -> int2 {
        v2h xh = pkrtz(x0, x1);
        v2h xl = pkrtz(x0 - (float)xh.x, x1 - (float)xh.y);
        int2 r; r.x = __builtin_bit_cast(int, xh); r.y = __builtin_bit_cast(int, xl);
        return r;
    };

    auto mfmaL0 = [&](int2 xw) -> v16f {
        v4i b; b.x = h0w0; b.y = h0w1; b.z = xw.x; b.w = xw.y;
        return __builtin_amdgcn_mfma_f32_32x32x16_f16(
            A0, __builtin_bit_cast(v8h, b), bias0, 0, 0, 0);
    };
    auto mfmaL1 = [&]() -> v16f {
        v4i b; b.x = h0w0; b.y = h0w1; b.z = h1w0; b.w = h1w1;
        return __builtin_amdgcn_mfma_f32_32x32x16_f16(
            A1, __builtin_bit_cast(v8h, b), bias1, 0, 0, 0);
    };
    auto actL0 = [&](const v16f& acc) {
        float nh[4];
        gates(acc, c0, nh);
        h0w0 = pk_rtn(nh[0], nh[1]);
        h0w1 = pk_rtn(nh[2], nh[3]);
    };
    auto actL1 = [&](const v16f& acc) {
        gates(acc, c1, h1f);
        h1w0 = pk_rtn(h1f[0], h1f[1]);
        h1w1 = pk_rtn(h1f[2], h1f[3]);
    };

    // dual step: L0(t+1) and L1(t) — both MFMAs read pre-update h0w/h1w
    auto dual = [&](float x0, float x1) {
        int2 xw = packx(x0, x1);
        v16f a0 = mfmaL0(xw);   // L0 next step
        v16f a1 = mfmaL1();     // L1 current step (reads old h0w before actL0)
        actL0(a0);
        actL1(a1);
    };

    // ---- prologue: L0(0), then dual(L0(1), L1(0)) ----
    {
        float4 xv = xp[0];
        v16f a0 = mfmaL0(packx(xv.x, xv.y));
        actL0(a0);
        dual(xv.z, xv.w);
    }
    // ---- main: it=1..127, steps (2it, 2it+1) for L0 ----
#pragma unroll 1
    for (int it = 1; it < TT / 2; ++it) {
        float4 xv = xp[it];
        dual(xv.x, xv.y);   // L0(2it),   L1(2it-1)
        dual(xv.z, xv.w);   // L0(2it+1), L1(2it)
    }
    // ---- epilogue: L1(255) ----
    {
        v16f a1 = mfmaL1();
        actL1(a1);
    }

    // ---- MLP head: own quad partial, xor(32) completes the dot ----
    const int q = 4 * hf;
    float p0 = 0.f, p1 = 0.f;
#pragma unroll
    for (int j = 0; j < 4; ++j) {
        p0 += w_mlp[q + j] * h1f[j];
        p1 += w_mlp[8 + q + j] * h1f[j];
    }
    p0 += __shfl_xor(p0, 32);
    p1 += __shfl_xor(p1, 32);
    if (hf == 0) {
        out[elem * 2 + 0] = p0 + b_mlp[0];
        out[elem * 2 + 1] = p1 + b_mlp[1];
    }
}

extern "C" void kernel_launch(void* const* d_in, const int* in_sizes, int n_in,
                              void* d_out, int out_size, void* d_ws, size_t ws_size,
                              hipStream_t stream) {
    const float* input = (const float*)d_in[0];
    const float* w_ih0 = (const float*)d_in[1];
    const float* w_hh0 = (const float*)d_in[2];
    const float* b_ih0 = (const float*)d_in[3];
    const float* b_hh0 = (const float*)d_in[4];
    const float* w_ih1 = (const float*)d_in[5];
    const float* w_hh1 = (const float*)d_in[6];
    const float* b_ih1 = (const float*)d_in[7];
    const float* b_hh1 = (const float*)d_in[8];
    const float* w_mlp = (const float*)d_in[9];
    const float* b_mlp = (const float*)d_in[10];
    float* out = (float*)d_out;

    // one wave per 32 batch elements: 1024 waves, 4 waves (256 thr) per block
    dim3 block(256);
    dim3 grid(NB / 128);
    lstm2_dual<<<grid, block, 0, stream>>>(input, w_ih0, w_hh0, b_ih0, b_hh0,
                                           w_ih1, w_hh1, b_ih1, b_hh1,
                                           w_mlp, b_mlp, out);
}